// Round 5
// baseline (413.676 us; speedup 1.0000x reference)
//
#include <hip/hip_runtime.h>

#define H 128

// ---------------------------------------------------------------------------
// R4: no CSR sort. Per-node 4-way linked lists:
//   entry[e] = (src, ea_bits, next, 0)  -- written COALESCED at index e
//   next     = atomicExch(&head[4*dst + (e&3)], e)
// Edge kernels walk 4 chains/node in parallel (wave-uniform loads, broadcast).
// Layer-1 (scalar) fused into build. t3 aliases bufA. No memsets.
//
// Workspace (4-byte words):
//   consts[1024] | entry[E*4] | bufA[N*H] (t2 -> t3) | h2b[N*H bf16]
//   | head[4N] | s1[N] | p[N] | q[N]
// ---------------------------------------------------------------------------

__device__ __forceinline__ float4 f4fma(float s, float4 w, float4 a) {
  a.x = fmaf(s, w.x, a.x); a.y = fmaf(s, w.y, a.y);
  a.z = fmaf(s, w.z, a.z); a.w = fmaf(s, w.w, a.w);
  return a;
}

__device__ __forceinline__ float bf2f(unsigned short v) {
  return __uint_as_float(((unsigned)v) << 16);
}

__device__ __forceinline__ unsigned bf16pair(float a, float b) {
  unsigned ua = __float_as_uint(a), ub = __float_as_uint(b);
  ua = (ua + 0x7FFFu + ((ua >> 16) & 1u)) >> 16;   // RNE
  ub = (ub + 0x7FFFu + ((ub >> 16) & 1u)) >> 16;
  return (ua & 0xFFFFu) | (ub << 16);
}

// last block: precompute folded constants; others: s1=x, head=-1
__global__ void init_kernel(
    const float* __restrict__ x, float* __restrict__ s1,
    int4* __restrict__ head, int N,
    const float* __restrict__ em_w, const float* __restrict__ em_b,
    const float* __restrict__ l1_w, const float* __restrict__ l1_b,
    const float* __restrict__ l2_w, const float* __restrict__ l2_b,
    const float* __restrict__ n1_b,
    const float* __restrict__ l3_w, const float* __restrict__ l3_b,
    float* __restrict__ consts) {
  if (blockIdx.x == gridDim.x - 1) {
    const int k = threadIdx.x;
    __shared__ float sa[H], sc[H];
    if (k < H) {
      float u2 = 0.f, c2 = 0.f, u3 = 0.f, c3 = 0.f;
      for (int j = 0; j < H; ++j) {
        const float ew = em_w[j], eb = em_b[j];
        u2 = fmaf(ew, l2_w[j * H + k], u2);
        c2 = fmaf(eb, l2_w[j * H + k], c2);
        u3 = fmaf(ew, l3_w[j * H + k], u3);
        c3 = fmaf(eb, l3_w[j * H + k], c3);
      }
      consts[2 + k]         = u2;
      consts[2 + H + k]     = c2 + l2_b[k] + n1_b[k];
      consts[2 + 2 * H + k] = u3;
      consts[2 + 3 * H + k] = c3 + l3_b[k];
      sa[k] = em_w[k] * l1_w[k];
      sc[k] = em_b[k] * l1_w[k];
    }
    __syncthreads();
    for (int s = 64; s > 0; s >>= 1) {
      if (k < s) { sa[k] += sa[k + s]; sc[k] += sc[k + s]; }
      __syncthreads();
    }
    if (k == 0) { consts[0] = sa[0]; consts[1] = sc[0] + l1_b[0]; }
  } else {
    const int n = blockIdx.x * blockDim.x + threadIdx.x;
    if (n < N) {
      s1[n] = x[n];
      head[n] = make_int4(-1, -1, -1, -1);
    }
  }
}

// entry write (coalesced) + head exchange + fused layer-1 scalar aggregation
__global__ void build_kernel(const int* __restrict__ src,
                             const int* __restrict__ dst,
                             const float* __restrict__ ea,
                             const float* __restrict__ x,
                             const float* __restrict__ consts,
                             uint4* __restrict__ entry,
                             int* __restrict__ head,
                             float* __restrict__ s1, int E) {
  const int e = blockIdx.x * blockDim.x + threadIdx.x;
  if (e >= E) return;
  const int s = src[e], d = dst[e];
  const float a = ea[e];
  const int prev = atomicExch(&head[4 * d + (e & 3)], e);
  entry[e] = make_uint4((unsigned)s, __float_as_uint(a), (unsigned)prev, 0u);
  const float m = fmaxf(x[s] + fmaf(consts[0], a, consts[1]), 0.f);
  unsafeAtomicAdd(&s1[d], m);
}

// ------------------------- layer 2 (chains) -------------------------
// t2[n,k] = s1[n]*n1w[k] + n1b[k] + sum relu(s1[src]*n1w[k] + ea*u2[k] + c2[k])
// wave per node; lane covers k=lane, lane+64; 4 chains walked in parallel
__global__ __launch_bounds__(256) void edge2_chain(
    const int4* __restrict__ head, const uint4* __restrict__ entry,
    const float* __restrict__ s1, const float* __restrict__ n1w,
    const float* __restrict__ n1b, const float* __restrict__ consts,
    float* __restrict__ t2, int N) {
  const int n = (blockIdx.x * blockDim.x + threadIdx.x) >> 6;
  const int lane = threadIdx.x & 63;
  if (n >= N) return;
  const float w0 = n1w[lane],            w1 = n1w[lane + 64];
  const float u0 = consts[2 + lane],     u1 = consts[2 + lane + 64];
  const float c0 = consts[2 + H + lane], c1 = consts[2 + H + lane + 64];
  const int4 hp = head[n];
  int p0 = hp.x, p1 = hp.y, p2 = hp.z, p3 = hp.w;
  float acc0 = 0.f, acc1 = 0.f;
  while ((p0 & p1 & p2 & p3) >= 0) {   // loop while any chain active
    uint4 e0 = make_uint4(0, 0, 0, 0), e1 = e0, e2 = e0, e3 = e0;
    if (p0 >= 0) e0 = entry[p0];
    if (p1 >= 0) e1 = entry[p1];
    if (p2 >= 0) e2 = entry[p2];
    if (p3 >= 0) e3 = entry[p3];
    if (p0 >= 0) {
      const float s = s1[e0.x], a = __uint_as_float(e0.y);
      acc0 += fmaxf(fmaf(s, w0, fmaf(a, u0, c0)), 0.f);
      acc1 += fmaxf(fmaf(s, w1, fmaf(a, u1, c1)), 0.f);
      p0 = (int)e0.z;
    }
    if (p1 >= 0) {
      const float s = s1[e1.x], a = __uint_as_float(e1.y);
      acc0 += fmaxf(fmaf(s, w0, fmaf(a, u0, c0)), 0.f);
      acc1 += fmaxf(fmaf(s, w1, fmaf(a, u1, c1)), 0.f);
      p1 = (int)e1.z;
    }
    if (p2 >= 0) {
      const float s = s1[e2.x], a = __uint_as_float(e2.y);
      acc0 += fmaxf(fmaf(s, w0, fmaf(a, u0, c0)), 0.f);
      acc1 += fmaxf(fmaf(s, w1, fmaf(a, u1, c1)), 0.f);
      p2 = (int)e2.z;
    }
    if (p3 >= 0) {
      const float s = s1[e3.x], a = __uint_as_float(e3.y);
      acc0 += fmaxf(fmaf(s, w0, fmaf(a, u0, c0)), 0.f);
      acc1 += fmaxf(fmaf(s, w1, fmaf(a, u1, c1)), 0.f);
      p3 = (int)e3.z;
    }
  }
  const float sn = s1[n];
  t2[(size_t)n * H + lane]      = fmaf(sn, w0, n1b[lane])      + acc0;
  t2[(size_t)n * H + lane + 64] = fmaf(sn, w1, n1b[lane + 64]) + acc1;
}

// ------------------------- layer 3 (chains, bf16 h2 gather) -----------------
// t3[n,k] = h2[n,k] + sum relu(h2[src,k] + ea*u3[k] + c3[k])
// lane covers k0=2*lane, k0+1 (one ushort2 per row per lane)
__global__ __launch_bounds__(256) void edge3_chain(
    const int4* __restrict__ head, const uint4* __restrict__ entry,
    const unsigned short* __restrict__ h2b, const float* __restrict__ consts,
    float* __restrict__ t3, int N) {
  const int n = (blockIdx.x * blockDim.x + threadIdx.x) >> 6;
  const int lane = threadIdx.x & 63;
  if (n >= N) return;
  const int k0 = 2 * lane;
  const float u0 = consts[2 + 2 * H + k0], u1 = consts[2 + 2 * H + k0 + 1];
  const float c0 = consts[2 + 3 * H + k0], c1 = consts[2 + 3 * H + k0 + 1];
  const int4 hp = head[n];
  int p0 = hp.x, p1 = hp.y, p2 = hp.z, p3 = hp.w;
  float acc0 = 0.f, acc1 = 0.f;
  while ((p0 & p1 & p2 & p3) >= 0) {
    uint4 e0 = make_uint4(0, 0, 0, 0), e1 = e0, e2 = e0, e3 = e0;
    if (p0 >= 0) e0 = entry[p0];
    if (p1 >= 0) e1 = entry[p1];
    if (p2 >= 0) e2 = entry[p2];
    if (p3 >= 0) e3 = entry[p3];
    unsigned h0 = 0, h1 = 0, h2v = 0, h3 = 0;
    if (p0 >= 0) h0  = *(const unsigned*)&h2b[(size_t)e0.x * H + k0];
    if (p1 >= 0) h1  = *(const unsigned*)&h2b[(size_t)e1.x * H + k0];
    if (p2 >= 0) h2v = *(const unsigned*)&h2b[(size_t)e2.x * H + k0];
    if (p3 >= 0) h3  = *(const unsigned*)&h2b[(size_t)e3.x * H + k0];
    if (p0 >= 0) {
      const float a = __uint_as_float(e0.y);
      acc0 += fmaxf(bf2f((unsigned short)h0)         + fmaf(a, u0, c0), 0.f);
      acc1 += fmaxf(bf2f((unsigned short)(h0 >> 16)) + fmaf(a, u1, c1), 0.f);
      p0 = (int)e0.z;
    }
    if (p1 >= 0) {
      const float a = __uint_as_float(e1.y);
      acc0 += fmaxf(bf2f((unsigned short)h1)         + fmaf(a, u0, c0), 0.f);
      acc1 += fmaxf(bf2f((unsigned short)(h1 >> 16)) + fmaf(a, u1, c1), 0.f);
      p1 = (int)e1.z;
    }
    if (p2 >= 0) {
      const float a = __uint_as_float(e2.y);
      acc0 += fmaxf(bf2f((unsigned short)h2v)         + fmaf(a, u0, c0), 0.f);
      acc1 += fmaxf(bf2f((unsigned short)(h2v >> 16)) + fmaf(a, u1, c1), 0.f);
      p2 = (int)e2.z;
    }
    if (p3 >= 0) {
      const float a = __uint_as_float(e3.y);
      acc0 += fmaxf(bf2f((unsigned short)h3)         + fmaf(a, u0, c0), 0.f);
      acc1 += fmaxf(bf2f((unsigned short)(h3 >> 16)) + fmaf(a, u1, c1), 0.f);
      p3 = (int)e3.z;
    }
  }
  const unsigned hn = *(const unsigned*)&h2b[(size_t)n * H + k0];
  float2 o;
  o.x = bf2f((unsigned short)hn)         + acc0;
  o.y = bf2f((unsigned short)(hn >> 16)) + acc1;
  *(float2*)&t3[(size_t)n * H + k0] = o;
}

// ------------------------- node MLPs -------------------------
// h2b = bf16(t2 @ n2w + n2b)
__global__ __launch_bounds__(256) void mlp2_kernel(
    const float* __restrict__ t2, unsigned short* __restrict__ h2b,
    const float* __restrict__ n2w, const float* __restrict__ n2b, int N) {
  __shared__ float W[H * H];
  __shared__ float t[32][H];
  const int tid = threadIdx.x;
  for (int i = tid; i < H * H; i += 256) W[i] = n2w[i];
  const int kv = tid & 31;
  const int ng = tid >> 5;
  const float4* W4 = (const float4*)W;
  const float4 bias = ((const float4*)n2b)[kv];
  for (int tile = blockIdx.x * 32; tile < N; tile += gridDim.x * 32) {
    __syncthreads();
    const int nmax = min(32, N - tile);
    for (int i = tid; i < nmax * 32; i += 256) {
      const int nn = i >> 5, j4 = i & 31;
      ((float4*)&t[nn][0])[j4] = ((const float4*)(t2 + (size_t)(tile + nn) * H))[j4];
    }
    __syncthreads();
    float4 acc[4];
    acc[0] = acc[1] = acc[2] = acc[3] = make_float4(0.f, 0.f, 0.f, 0.f);
    for (int j = 0; j < H; j += 4) {
      const float4 w0 = W4[(j + 0) * 32 + kv];
      const float4 w1 = W4[(j + 1) * 32 + kv];
      const float4 w2 = W4[(j + 2) * 32 + kv];
      const float4 w3 = W4[(j + 3) * 32 + kv];
#pragma unroll
      for (int m = 0; m < 4; ++m) {
        const float4 tm = *(const float4*)&t[4 * ng + m][j];
        acc[m] = f4fma(tm.x, w0, acc[m]);
        acc[m] = f4fma(tm.y, w1, acc[m]);
        acc[m] = f4fma(tm.z, w2, acc[m]);
        acc[m] = f4fma(tm.w, w3, acc[m]);
      }
    }
#pragma unroll
    for (int m = 0; m < 4; ++m) {
      const int nn = 4 * ng + m;
      if (nn < nmax) {
        uint2 st;
        st.x = bf16pair(acc[m].x + bias.x, acc[m].y + bias.y);
        st.y = bf16pair(acc[m].z + bias.z, acc[m].w + bias.w);
        ((uint2*)(h2b + (size_t)(tile + nn) * H))[kv] = st;
      }
    }
  }
}

// h3 = t3 @ n3w + n3b; p[n]=h3.dec_w[:128]; q[n]=h3.dec_w[128:]
__global__ __launch_bounds__(256) void mlp3_kernel(
    const float* __restrict__ t3, const float* __restrict__ n3w,
    const float* __restrict__ n3b, const float* __restrict__ dec_w,
    float* __restrict__ p, float* __restrict__ q, int N) {
  __shared__ float W[H * H];
  __shared__ float t[32][H];
  const int tid = threadIdx.x;
  for (int i = tid; i < H * H; i += 256) W[i] = n3w[i];
  const int kv = tid & 31;
  const int ng = tid >> 5;
  const float4* W4 = (const float4*)W;
  const float4 bias = ((const float4*)n3b)[kv];
  const float4 dwA = ((const float4*)dec_w)[kv];
  const float4 dwB = ((const float4*)(dec_w + H))[kv];
  for (int tile = blockIdx.x * 32; tile < N; tile += gridDim.x * 32) {
    __syncthreads();
    const int nmax = min(32, N - tile);
    for (int i = tid; i < nmax * 32; i += 256) {
      const int nn = i >> 5, j4 = i & 31;
      ((float4*)&t[nn][0])[j4] = ((const float4*)(t3 + (size_t)(tile + nn) * H))[j4];
    }
    __syncthreads();
    float4 acc[4];
    acc[0] = acc[1] = acc[2] = acc[3] = make_float4(0.f, 0.f, 0.f, 0.f);
    for (int j = 0; j < H; j += 4) {
      const float4 w0 = W4[(j + 0) * 32 + kv];
      const float4 w1 = W4[(j + 1) * 32 + kv];
      const float4 w2 = W4[(j + 2) * 32 + kv];
      const float4 w3 = W4[(j + 3) * 32 + kv];
#pragma unroll
      for (int m = 0; m < 4; ++m) {
        const float4 tm = *(const float4*)&t[4 * ng + m][j];
        acc[m] = f4fma(tm.x, w0, acc[m]);
        acc[m] = f4fma(tm.y, w1, acc[m]);
        acc[m] = f4fma(tm.z, w2, acc[m]);
        acc[m] = f4fma(tm.w, w3, acc[m]);
      }
    }
#pragma unroll
    for (int m = 0; m < 4; ++m) {
      float4 h;
      h.x = acc[m].x + bias.x; h.y = acc[m].y + bias.y;
      h.z = acc[m].z + bias.z; h.w = acc[m].w + bias.w;
      float pd = h.x * dwA.x + h.y * dwA.y + h.z * dwA.z + h.w * dwA.w;
      float qd = h.x * dwB.x + h.y * dwB.y + h.z * dwB.z + h.w * dwB.w;
#pragma unroll
      for (int o = 16; o >= 1; o >>= 1) {
        pd += __shfl_xor(pd, o, 64);
        qd += __shfl_xor(qd, o, 64);
      }
      const int n = tile + 4 * ng + m;
      if (kv == 0 && 4 * ng + m < nmax) { p[n] = pd; q[n] = qd; }
    }
  }
}

__global__ void final_kernel(const int* __restrict__ src,
                             const int* __restrict__ dst,
                             const float* __restrict__ p,
                             const float* __restrict__ q,
                             const float* __restrict__ dec_b,
                             float* __restrict__ out, int E) {
  const int e = blockIdx.x * blockDim.x + threadIdx.x;
  if (e < E) out[e] = p[src[e]] + q[dst[e]] + dec_b[0];
}

extern "C" void kernel_launch(void* const* d_in, const int* in_sizes, int n_in,
                              void* d_out, int out_size, void* d_ws, size_t ws_size,
                              hipStream_t stream) {
  const float* x     = (const float*)d_in[0];
  const int*   ei    = (const int*)d_in[1];
  const float* ea    = (const float*)d_in[2];
  const float* em_w  = (const float*)d_in[3];
  const float* em_b  = (const float*)d_in[4];
  const float* l1_w  = (const float*)d_in[5];
  const float* l1_b  = (const float*)d_in[6];
  const float* n1_w  = (const float*)d_in[7];
  const float* n1_b  = (const float*)d_in[8];
  const float* l2_w  = (const float*)d_in[9];
  const float* l2_b  = (const float*)d_in[10];
  const float* n2_w  = (const float*)d_in[11];
  const float* n2_b  = (const float*)d_in[12];
  const float* l3_w  = (const float*)d_in[13];
  const float* l3_b  = (const float*)d_in[14];
  const float* n3_w  = (const float*)d_in[15];
  const float* n3_b  = (const float*)d_in[16];
  const float* dec_w = (const float*)d_in[17];
  const float* dec_b = (const float*)d_in[18];
  float* out = (float*)d_out;

  const int N = in_sizes[0];
  const int E = in_sizes[2];
  const int* src = ei;
  const int* dst = ei + E;

  float* ws       = (float*)d_ws;
  float* consts   = ws;                              // 1024 f
  uint4* entry    = (uint4*)(ws + 1024);             // E * 16 B (16B-aligned)
  float* bufA     = (float*)(entry + E);             // N*H f (t2, then t3)
  unsigned short* h2b = (unsigned short*)(bufA + (size_t)N * H);  // N*H bf16
  int*   head     = (int*)(h2b + (size_t)N * H);     // 4N ints (16B-aligned)
  float* s1       = (float*)(head + 4 * (size_t)N);
  float* p        = s1 + N;
  float* q        = p + N;

  const int nwblocks = (N + 3) / 4;  // 4 waves (nodes) per 256-thread block

  init_kernel<<<(N + 255) / 256 + 1, 256, 0, stream>>>(
      x, s1, (int4*)head, N, em_w, em_b, l1_w, l1_b, l2_w, l2_b, n1_b,
      l3_w, l3_b, consts);
  build_kernel<<<(E + 255) / 256, 256, 0, stream>>>(src, dst, ea, x, consts,
                                                    entry, head, s1, E);
  edge2_chain<<<nwblocks, 256, 0, stream>>>((const int4*)head, entry, s1,
                                            n1_w, n1_b, consts, bufA, N);
  mlp2_kernel<<<512, 256, 0, stream>>>(bufA, h2b, n2_w, n2_b, N);
  edge3_chain<<<nwblocks, 256, 0, stream>>>((const int4*)head, entry, h2b,
                                            consts, bufA, N);
  mlp3_kernel<<<512, 256, 0, stream>>>(bufA, n3_w, n3_b, dec_w, p, q, N);
  final_kernel<<<(E + 255) / 256, 256, 0, stream>>>(src, dst, p, q, dec_b, out, E);
}